// Round 4
// baseline (211.838 us; speedup 1.0000x reference)
//
#include <hip/hip_runtime.h>
#include <hip/hip_bf16.h>

#define BATCH 16
#define C 768
#define T 8
#define R 64
#define HW 4096
#define NPS (HW*C)   // 3145728 elements per sample
#define GN_EPS 1e-5f

typedef short bf16x8 __attribute__((ext_vector_type(8)));
typedef float f32x4 __attribute__((ext_vector_type(4)));

static __device__ __forceinline__ unsigned short f2bf(float f) {
    __hip_bfloat16 h = __float2bfloat16(f);
    return *reinterpret_cast<unsigned short*>(&h);
}

// ---------------- kernel 1: zero stats + convert weights to bf16 ----------------
__global__ __launch_bounds__(256) void prep_kernel(const float* __restrict__ Wdn,
                                                   const float* __restrict__ Wup,
                                                   float* __restrict__ stats,
                                                   unsigned short* __restrict__ wd_bf,
                                                   unsigned short* __restrict__ wu_bf) {
    int idx = blockIdx.x * 256 + threadIdx.x;   // 0..196607, each handles one float4
    if (blockIdx.x == 0 && threadIdx.x < 32) stats[threadIdx.x] = 0.f;
    const int NF4 = T * R * C / 4;              // 98304 float4 per weight tensor
    const float4* src;
    unsigned short* dst;
    int j;
    if (idx < NF4) { src = (const float4*)Wdn; dst = wd_bf; j = idx; }
    else           { src = (const float4*)Wup; dst = wu_bf; j = idx - NF4; }
    float4 v = src[j];
    ushort4 o;
    o.x = f2bf(v.x); o.y = f2bf(v.y); o.z = f2bf(v.z); o.w = f2bf(v.w);
    *reinterpret_cast<ushort4*>(dst + j * 4) = o;
}

// ---------------- kernel 2: per-sample sum / sumsq ----------------
__global__ __launch_bounds__(256) void stats_kernel(const float* __restrict__ x,
                                                    float* __restrict__ stats) {
    int b = blockIdx.y;
    const float4* xp = (const float4*)(x + (size_t)b * NPS);
    float s = 0.f, q = 0.f;
    int base = blockIdx.x * 256 + threadIdx.x;  // grid.x = 48 -> 12288 threads
    #pragma unroll 4
    for (int i = 0; i < 64; i++) {
        float4 v = xp[(size_t)i * 12288 + base];
        s += v.x + v.y + v.z + v.w;
        q += v.x*v.x + v.y*v.y + v.z*v.z + v.w*v.w;
    }
    for (int off = 32; off > 0; off >>= 1) {
        s += __shfl_down(s, off);
        q += __shfl_down(q, off);
    }
    __shared__ float ps[4], pq[4];
    int wave = threadIdx.x >> 6, lane = threadIdx.x & 63;
    if (lane == 0) { ps[wave] = s; pq[wave] = q; }
    __syncthreads();
    if (threadIdx.x == 0) {
        float S = 0.f, Q = 0.f;
        #pragma unroll
        for (int wv = 0; wv < 4; wv++) { S += ps[wv]; Q += pq[wv]; }
        atomicAdd(&stats[2*b],   S);
        atomicAdd(&stats[2*b+1], Q);
    }
}

// ---------------- kernel 3: fused normalize + GEMM1 + gelu + GEMM2 + residual ----------------
// grid (64 tiles, 16 samples), 256 threads = 4 waves, each wave owns 16 x-rows.
// Operand-swapped MFMAs: A = weights, B = activations^T -> vectorized epilogue.
// MLP fix: GEMM1 issues 16 back-to-back float4 loads (8 k-iters) per super-batch
// before consuming; epilogue hoists each cn-group's 8 residual loads ahead of
// its MFMAs. Keeps ~16KB/wave outstanding instead of ~0.5KB.
__global__ __launch_bounds__(256, 4) void fused_kernel(
        const float* __restrict__ x, const int* __restrict__ task_ids,
        const float* __restrict__ gamma, const float* __restrict__ beta,
        const float* __restrict__ scales, const float* __restrict__ stats,
        const unsigned short* __restrict__ wd_bf, const unsigned short* __restrict__ wu_bf,
        float* __restrict__ out) {
    __shared__ float coefA[C];                // rstd*gamma
    __shared__ float coefB[C];                // beta - mean*rstd*gamma
    __shared__ unsigned short hs[64 * 64];    // 8 KiB gelu(h), row stride 128B, XOR-swizzled

    int tile = blockIdx.x, b = blockIdx.y;
    int tid = threadIdx.x;
    int t = task_ids[b];
    float sc = scales[t];
    float s1 = stats[2*b], s2 = stats[2*b+1];
    float mean = s1 * (1.f / NPS);
    float var  = s2 * (1.f / NPS) - mean * mean;
    float rstd = rsqrtf(var + GN_EPS);

    // ---- stage normalization coefficients into LDS (one-time) ----
    if (tid < 192) {
        float4 g  = ((const float4*)gamma)[tid];
        float4 be = ((const float4*)beta)[tid];
        float4 ca, cb;
        ca.x = rstd * g.x; cb.x = be.x - mean * ca.x;
        ca.y = rstd * g.y; cb.y = be.y - mean * ca.y;
        ca.z = rstd * g.z; cb.z = be.z - mean * ca.z;
        ca.w = rstd * g.w; cb.w = be.w - mean * ca.w;
        ((float4*)coefA)[tid] = ca;
        ((float4*)coefB)[tid] = cb;
    }
    __syncthreads();

    size_t xbase = (size_t)b * NPS + (size_t)tile * 64 * C;
    int wave = tid >> 6, lane = tid & 63;
    int m0 = wave * 16;
    int lr = lane & 15, lg = lane >> 4;
    int row = m0 + lr;                        // this lane's x-row (B-frag column)

    // ---- GEMM1: h^T[R x 64rows] = Wd[R x C] * x_norm^T, A=Wd, B=x_norm^T ----
    const unsigned short* wd = wd_bf + t * (R * C);
    const float* xb = x + xbase + (size_t)row * C + lg * 8;  // lane's k-strip base
    f32x4 acc1[4] = {};
    for (int sb = 0; sb < 3; sb++) {
        // issue 16 independent float4 loads back-to-back (8 k-iters' data)
        float4 buf0[8], buf1[8];
        #pragma unroll
        for (int i = 0; i < 8; i++) {
            int k = sb * 8 + i;
            buf0[i] = *reinterpret_cast<const float4*>(xb + k * 32);
            buf1[i] = *reinterpret_cast<const float4*>(xb + k * 32 + 4);
        }
        // consume in issue order
        #pragma unroll
        for (int i = 0; i < 8; i++) {
            int k = sb * 8 + i;
            int col = k * 32 + lg * 8;
            float4 ca0 = *reinterpret_cast<const float4*>(coefA + col);
            float4 ca1 = *reinterpret_cast<const float4*>(coefA + col + 4);
            float4 cb0 = *reinterpret_cast<const float4*>(coefB + col);
            float4 cb1 = *reinterpret_cast<const float4*>(coefB + col + 4);
            bf16x8 bfv;
            bfv[0] = (short)f2bf(buf0[i].x * ca0.x + cb0.x);
            bfv[1] = (short)f2bf(buf0[i].y * ca0.y + cb0.y);
            bfv[2] = (short)f2bf(buf0[i].z * ca0.z + cb0.z);
            bfv[3] = (short)f2bf(buf0[i].w * ca0.w + cb0.w);
            bfv[4] = (short)f2bf(buf1[i].x * ca1.x + cb1.x);
            bfv[5] = (short)f2bf(buf1[i].y * ca1.y + cb1.y);
            bfv[6] = (short)f2bf(buf1[i].z * ca1.z + cb1.z);
            bfv[7] = (short)f2bf(buf1[i].w * ca1.w + cb1.w);
            #pragma unroll
            for (int rg = 0; rg < 4; rg++) {
                bf16x8 af = *reinterpret_cast<const bf16x8*>(wd + (rg * 16 + lr) * C + k * 32 + lg * 8);
                acc1[rg] = __builtin_amdgcn_mfma_f32_16x16x32_bf16(af, bfv, acc1[rg], 0, 0, 0);
            }
        }
    }

    // ---- exact gelu; h -> swizzled LDS. D: row=R-chan (lg*4+j), col=x-row (lr) ----
    char* hsb = (char*)hs;
    #pragma unroll
    for (int rg = 0; rg < 4; rg++) {
        ushort4 o;
        float v0 = acc1[rg][0], v1 = acc1[rg][1], v2 = acc1[rg][2], v3 = acc1[rg][3];
        o.x = f2bf(0.5f * v0 * (1.f + erff(v0 * 0.70710678118f)));
        o.y = f2bf(0.5f * v1 * (1.f + erff(v1 * 0.70710678118f)));
        o.z = f2bf(0.5f * v2 * (1.f + erff(v2 * 0.70710678118f)));
        o.w = f2bf(0.5f * v3 * (1.f + erff(v3 * 0.70710678118f)));
        // h[row=x-row][chan]: x-row = m0+lr, chan = rg*16 + lg*4 .. +3  (8B write)
        int byte = (m0 + lr) * 128 + rg * 32 + lg * 8;
        byte ^= ((lr & 7) << 4);
        *reinterpret_cast<ushort4*>(hsb + byte) = o;
    }
    // hs rows are wave-private (each wave reads only its own 16 rows) -> no barrier.

    // ---- GEMM2: delta^T[C x 64rows] = Wu[C x R] * h^T, fused residual ----
    bf16x8 b2[2];
    #pragma unroll
    for (int k2 = 0; k2 < 2; k2++) {
        int byte = row * 128 + k2 * 64 + lg * 16;
        byte ^= ((lr & 7) << 4);
        b2[k2] = *reinterpret_cast<const bf16x8*>(hsb + byte);
    }
    const unsigned short* wu = wu_bf + t * (C * R);
    const float* xr = x + xbase;
    float* outp = out + xbase;
    for (int cn = 0; cn < 6; cn++) {
        // hoist residual loads for this group ahead of its MFMAs
        float4 xv[8];
        #pragma unroll
        for (int cg = 0; cg < 8; cg++) {
            int c0 = cn * 128 + cg * 16 + lg * 4;
            xv[cg] = *reinterpret_cast<const float4*>(xr + (size_t)row * C + c0);
        }
        f32x4 acc2[8] = {};
        #pragma unroll
        for (int cg = 0; cg < 8; cg++) {
            int crow = cn * 128 + cg * 16 + lr;
            bf16x8 a0 = *reinterpret_cast<const bf16x8*>(wu + crow * R + lg * 8);
            bf16x8 a1 = *reinterpret_cast<const bf16x8*>(wu + crow * R + 32 + lg * 8);
            acc2[cg] = __builtin_amdgcn_mfma_f32_16x16x32_bf16(a0, b2[0], acc2[cg], 0, 0, 0);
            acc2[cg] = __builtin_amdgcn_mfma_f32_16x16x32_bf16(a1, b2[1], acc2[cg], 0, 0, 0);
        }
        #pragma unroll
        for (int cg = 0; cg < 8; cg++) {
            int c0 = cn * 128 + cg * 16 + lg * 4;
            size_t off = (size_t)row * C + c0;
            float4 ov;
            ov.x = xv[cg].x + sc * acc2[cg][0];
            ov.y = xv[cg].y + sc * acc2[cg][1];
            ov.z = xv[cg].z + sc * acc2[cg][2];
            ov.w = xv[cg].w + sc * acc2[cg][3];
            *reinterpret_cast<float4*>(outp + off) = ov;
        }
    }
}

extern "C" void kernel_launch(void* const* d_in, const int* in_sizes, int n_in,
                              void* d_out, int out_size, void* d_ws, size_t ws_size,
                              hipStream_t stream) {
    const float* x        = (const float*)d_in[0];
    const int*   task_ids = (const int*)d_in[1];
    const float* gamma    = (const float*)d_in[2];
    const float* beta     = (const float*)d_in[3];
    const float* W_down   = (const float*)d_in[4];
    const float* W_up     = (const float*)d_in[5];
    const float* scales   = (const float*)d_in[6];
    float* out = (float*)d_out;

    // workspace layout: [0,128): stats (16 x {sum,sumsq}); then bf16 weights
    float* stats = (float*)d_ws;
    unsigned short* wd_bf = (unsigned short*)((char*)d_ws + 128);
    unsigned short* wu_bf = wd_bf + T * R * C;

    // 1) zero stats + convert weights (2*98304 float4 jobs / 256 = 768 blocks)
    prep_kernel<<<768, 256, 0, stream>>>(W_down, W_up, stats, wd_bf, wu_bf);
    // 2) per-sample stats
    stats_kernel<<<dim3(48, BATCH), 256, 0, stream>>>(x, stats);
    // 3) fused adapter
    fused_kernel<<<dim3(64, BATCH), 256, 0, stream>>>(
        x, task_ids, gamma, beta, scales, stats, wd_bf, wu_bf, out);
}

// Round 5
// 139.797 us; speedup vs baseline: 1.5153x; 1.5153x over previous
//
#include <hip/hip_runtime.h>
#include <hip/hip_bf16.h>

#define BATCH 16
#define C 768
#define T 8
#define R 64
#define HW 4096
#define NPS (HW*C)   // 3145728 elements per sample
#define GN_EPS 1e-5f

typedef short bf16x8 __attribute__((ext_vector_type(8)));
typedef float f32x4 __attribute__((ext_vector_type(4)));

static __device__ __forceinline__ unsigned short f2bf(float f) {
    __hip_bfloat16 h = __float2bfloat16(f);
    return *reinterpret_cast<unsigned short*>(&h);
}

// ---------------- kernel 1: prep ----------------
// blocks 0..767: zero stats + convert Wd*gamma and Wu to bf16
// blocks 768..895: per-(task,r) dots u = Wd·gamma, w = Wd·beta
__global__ __launch_bounds__(256) void prep_kernel(
        const float* __restrict__ Wdn, const float* __restrict__ Wup,
        const float* __restrict__ gamma, const float* __restrict__ beta,
        float* __restrict__ stats,
        unsigned short* __restrict__ wdg, unsigned short* __restrict__ wu_bf,
        float* __restrict__ u, float* __restrict__ w) {
    int bid = blockIdx.x;
    if (bid < 768) {
        int idx = bid * 256 + threadIdx.x;      // 0..196607 float4 jobs
        if (bid == 0 && threadIdx.x < 32) stats[threadIdx.x] = 0.f;
        const int NF4 = T * R * C / 4;          // 98304
        if (idx < NF4) {
            int c4 = idx % (C / 4);
            float4 v = ((const float4*)Wdn)[idx];
            float4 g = ((const float4*)gamma)[c4];
            ushort4 o;
            o.x = f2bf(v.x * g.x); o.y = f2bf(v.y * g.y);
            o.z = f2bf(v.z * g.z); o.w = f2bf(v.w * g.w);
            *reinterpret_cast<ushort4*>(wdg + idx * 4) = o;
        } else {
            int j = idx - NF4;
            float4 v = ((const float4*)Wup)[j];
            ushort4 o;
            o.x = f2bf(v.x); o.y = f2bf(v.y); o.z = f2bf(v.z); o.w = f2bf(v.w);
            *reinterpret_cast<ushort4*>(wu_bf + j * 4) = o;
        }
    } else {
        // 128 blocks x 4 rows: rowid = t*64 + r
        int rowid = (bid - 768) * 4 + (threadIdx.x >> 6);
        int lane = threadIdx.x & 63;
        const float* wrow = Wdn + (size_t)rowid * C;
        float su = 0.f, sw = 0.f;
        #pragma unroll
        for (int j = 0; j < 12; j++) {
            int c = lane + j * 64;
            float wv = wrow[c];
            su += wv * gamma[c];
            sw += wv * beta[c];
        }
        for (int off = 32; off > 0; off >>= 1) {
            su += __shfl_down(su, off);
            sw += __shfl_down(sw, off);
        }
        if (lane == 0) { u[rowid] = su; w[rowid] = sw; }
    }
}

// ---------------- kernel 2: per-sample sum / sumsq ----------------
__global__ __launch_bounds__(256) void stats_kernel(const float* __restrict__ x,
                                                    float* __restrict__ stats) {
    int b = blockIdx.y;
    const float4* xp = (const float4*)(x + (size_t)b * NPS);
    float s = 0.f, q = 0.f;
    int base = blockIdx.x * 256 + threadIdx.x;  // grid.x = 48 -> 12288 threads
    #pragma unroll 4
    for (int i = 0; i < 64; i++) {
        float4 v = xp[(size_t)i * 12288 + base];
        s += v.x + v.y + v.z + v.w;
        q += v.x*v.x + v.y*v.y + v.z*v.z + v.w*v.w;
    }
    for (int off = 32; off > 0; off >>= 1) {
        s += __shfl_down(s, off);
        q += __shfl_down(q, off);
    }
    __shared__ float ps[4], pq[4];
    int wave = threadIdx.x >> 6, lane = threadIdx.x & 63;
    if (lane == 0) { ps[wave] = s; pq[wave] = q; }
    __syncthreads();
    if (threadIdx.x == 0) {
        float S = 0.f, Q = 0.f;
        #pragma unroll
        for (int wv = 0; wv < 4; wv++) { S += ps[wv]; Q += pq[wv]; }
        atomicAdd(&stats[2*b],   S);
        atomicAdd(&stats[2*b+1], Q);
    }
}

// ---------------- kernel 3: fused, async-DMA double-buffered ----------------
// 256 blocks (1/CU), 256 threads = 4 waves. Block = (sample b, chunk of 256 rows),
// processes 16 tiles of 16 rows. x tile (48KB fp32) staged via global_load_lds
// with pre-swizzled source (XOR (row&7)<<4), double buffered, counted vmcnt(12).
// GroupNorm folded into weights: h_pre = rstd*(Wdg·x_raw) + (w - rstd*mean*u).
// All weight fragments persistent in VGPRs (1 wave/SIMD -> 512 VGPR budget).
__global__ __launch_bounds__(256, 1) void fused_kernel(
        const float* __restrict__ x, const int* __restrict__ task_ids,
        const float* __restrict__ scales, const float* __restrict__ stats,
        const unsigned short* __restrict__ wdg, const unsigned short* __restrict__ wu_bf,
        const float* __restrict__ u, const float* __restrict__ w,
        float* __restrict__ out) {
    __shared__ char xsb[2 * 49152];            // 96 KiB: 2 x (16 rows x 3072 B)
    __shared__ char hsb[2048];                 // 16 rows x 128 B bf16 h

    int bid = blockIdx.x;
    int b = bid >> 4;
    int chunk = bid & 15;
    int tid = threadIdx.x;
    int wv = tid >> 6, lane = tid & 63;
    int lr = lane & 15, lg = lane >> 4;
    int swz = (lr & 7) << 4;

    int t = task_ids[b];
    float sc = scales[t];
    float s1 = stats[2*b], s2 = stats[2*b+1];
    float mean = s1 * (1.f / NPS);
    float var  = s2 * (1.f / NPS) - mean * mean;
    float rstd = rsqrtf(var + GN_EPS);

    // persistent A-fragments (weights) in VGPRs
    const unsigned short* wdp = wdg + t * (R * C);
    bf16x8 a1[24];
    #pragma unroll
    for (int k = 0; k < 24; k++)
        a1[k] = *reinterpret_cast<const bf16x8*>(wdp + (wv * 16 + lr) * C + k * 32 + lg * 8);
    const unsigned short* wup = wu_bf + t * (C * R);
    bf16x8 a2[12][2];
    #pragma unroll
    for (int cb = 0; cb < 12; cb++)
        #pragma unroll
        for (int ks = 0; ks < 2; ks++)
            a2[cb][ks] = *reinterpret_cast<const bf16x8*>(
                wup + (wv * 192 + cb * 16 + lr) * R + ks * 32 + lg * 8);

    // gelu bias for this thread's 4 R-channels (r0..r0+3)
    int r0 = wv * 16 + lg * 4;
    float4 u4 = *reinterpret_cast<const float4*>(u + t * 64 + r0);
    float4 w4 = *reinterpret_cast<const float4*>(w + t * 64 + r0);
    float mb = rstd * mean;
    float bias0 = w4.x - mb * u4.x, bias1 = w4.y - mb * u4.y;
    float bias2 = w4.z - mb * u4.z, bias3 = w4.w - mb * u4.w;

    size_t base = (size_t)b * NPS + (size_t)chunk * 256 * C;   // elements
    const char* xbase_c = (const char*)(x + base);
    float* outp = out + base;
    const char* hcb = hsb;

#define STAGE(bufsel, tileidx) do {                                              \
    const char* _gs = xbase_c + (size_t)(tileidx) * 49152;                       \
    char* _ld = xsb + (bufsel) * 49152;                                          \
    _Pragma("unroll")                                                            \
    for (int _jj = 0; _jj < 12; _jj++) {                                         \
        int _j = wv * 12 + _jj;                                                  \
        int _row = _j / 3;                                                       \
        int _sub = _j - _row * 3;                                                \
        int _cb = (_sub * 1024 + lane * 16) ^ ((_row & 7) << 4);                 \
        __builtin_amdgcn_global_load_lds(                                        \
            (const __attribute__((address_space(1))) void*)(_gs + _row * 3072 + _cb), \
            (__attribute__((address_space(3))) void*)(_ld + (size_t)_j * 1024),  \
            16, 0, 0);                                                           \
    }                                                                            \
} while (0)

    STAGE(0, 0);   // prologue: tile 0 into buf 0

    int cur = 0;
    for (int i = 0; i < 16; i++) {
        if (i < 15) {
            STAGE(cur ^ 1, i + 1);
            asm volatile("s_waitcnt vmcnt(12)" ::: "memory");
        } else {
            asm volatile("s_waitcnt vmcnt(0)" ::: "memory");
        }
        __builtin_amdgcn_s_barrier();

        const char* xb = xsb + cur * 49152;

        // ---- GEMM1: G = Wdg · x_raw ; wave wv owns R-rows wv*16..+15 ----
        f32x4 acc1 = {0.f, 0.f, 0.f, 0.f};
        #pragma unroll
        for (int k = 0; k < 24; k++) {
            int cb0 = (k * 128 + lg * 32) ^ swz;
            int cb1 = (k * 128 + lg * 32 + 16) ^ swz;
            f32x4 xv0 = *reinterpret_cast<const f32x4*>(xb + lr * 3072 + cb0);
            f32x4 xv1 = *reinterpret_cast<const f32x4*>(xb + lr * 3072 + cb1);
            bf16x8 bfrag;
            bfrag[0] = (short)f2bf(xv0[0]); bfrag[1] = (short)f2bf(xv0[1]);
            bfrag[2] = (short)f2bf(xv0[2]); bfrag[3] = (short)f2bf(xv0[3]);
            bfrag[4] = (short)f2bf(xv1[0]); bfrag[5] = (short)f2bf(xv1[1]);
            bfrag[6] = (short)f2bf(xv1[2]); bfrag[7] = (short)f2bf(xv1[3]);
            acc1 = __builtin_amdgcn_mfma_f32_16x16x32_bf16(a1[k], bfrag, acc1, 0, 0, 0);
        }

        // ---- gelu(rstd*G + bias) -> hs (bf16, swizzled) ----
        {
            float v0 = rstd * acc1[0] + bias0;
            float v1 = rstd * acc1[1] + bias1;
            float v2 = rstd * acc1[2] + bias2;
            float v3 = rstd * acc1[3] + bias3;
            ushort4 o;
            o.x = f2bf(0.5f * v0 * (1.f + erff(v0 * 0.70710678118f)));
            o.y = f2bf(0.5f * v1 * (1.f + erff(v1 * 0.70710678118f)));
            o.z = f2bf(0.5f * v2 * (1.f + erff(v2 * 0.70710678118f)));
            o.w = f2bf(0.5f * v3 * (1.f + erff(v3 * 0.70710678118f)));
            int byte = lr * 128 + ((wv * 32 + lg * 8) ^ swz);
            *reinterpret_cast<ushort4*>(hsb + byte) = o;
        }
        asm volatile("s_waitcnt lgkmcnt(0)" ::: "memory");
        __builtin_amdgcn_s_barrier();

        // ---- GEMM2: delta = Wu · gelu(h); fused residual from LDS fp32 x ----
        bf16x8 b2[2];
        #pragma unroll
        for (int ks = 0; ks < 2; ks++) {
            int byte = lr * 128 + ((ks * 64 + lg * 16) ^ swz);
            b2[ks] = *reinterpret_cast<const bf16x8*>(hcb + byte);
        }
        size_t ro = (size_t)(i * 16 + lr) * C;
        #pragma unroll
        for (int cb = 0; cb < 12; cb++) {
            f32x4 acc = {0.f, 0.f, 0.f, 0.f};
            acc = __builtin_amdgcn_mfma_f32_16x16x32_bf16(a2[cb][0], b2[0], acc, 0, 0, 0);
            acc = __builtin_amdgcn_mfma_f32_16x16x32_bf16(a2[cb][1], b2[1], acc, 0, 0, 0);
            int c0 = wv * 192 + cb * 16 + lg * 4;
            float4 xr = *reinterpret_cast<const float4*>(xb + lr * 3072 + ((c0 * 4) ^ swz));
            float4 ov;
            ov.x = xr.x + sc * acc[0];
            ov.y = xr.y + sc * acc[1];
            ov.z = xr.z + sc * acc[2];
            ov.w = xr.w + sc * acc[3];
            *reinterpret_cast<float4*>(outp + ro + c0) = ov;
        }
        __builtin_amdgcn_s_barrier();
        asm volatile("" ::: "memory");
        cur ^= 1;
    }
#undef STAGE
}

extern "C" void kernel_launch(void* const* d_in, const int* in_sizes, int n_in,
                              void* d_out, int out_size, void* d_ws, size_t ws_size,
                              hipStream_t stream) {
    const float* x        = (const float*)d_in[0];
    const int*   task_ids = (const int*)d_in[1];
    const float* gamma    = (const float*)d_in[2];
    const float* beta     = (const float*)d_in[3];
    const float* W_down   = (const float*)d_in[4];
    const float* W_up     = (const float*)d_in[5];
    const float* scales   = (const float*)d_in[6];
    float* out = (float*)d_out;

    // workspace: [0,128) stats; wdg bf16; wu bf16; u fp32[512]; w fp32[512]
    float* stats = (float*)d_ws;
    unsigned short* wdg   = (unsigned short*)((char*)d_ws + 128);
    unsigned short* wu_bf = wdg + T * R * C;
    float* u = (float*)((char*)d_ws + 128 + 2 * T * R * C * sizeof(unsigned short));
    float* w = u + T * R;

    prep_kernel<<<896, 256, 0, stream>>>(W_down, W_up, gamma, beta, stats, wdg, wu_bf, u, w);
    stats_kernel<<<dim3(48, BATCH), 256, 0, stream>>>(x, stats);
    fused_kernel<<<256, 256, 0, stream>>>(x, task_ids, scales, stats, wdg, wu_bf, u, w, out);
}

// Round 6
// 120.723 us; speedup vs baseline: 1.7548x; 1.1580x over previous
//
#include <hip/hip_runtime.h>
#include <hip/hip_bf16.h>

#define BATCH 16
#define C 768
#define T 8
#define R 64
#define HW 4096
#define NPS (HW*C)   // 3145728 elements per sample
#define GN_EPS 1e-5f
#define NPART 48     // stats partial blocks per sample

typedef short bf16x8 __attribute__((ext_vector_type(8)));
typedef float f32x4 __attribute__((ext_vector_type(4)));

static __device__ __forceinline__ unsigned short f2bf(float f) {
    __hip_bfloat16 h = __float2bfloat16(f);
    return *reinterpret_cast<unsigned short*>(&h);
}

// ---------------- kernel A: prep (weights) + stats partials, one launch ----------------
// blocks 0..767   : convert Wd*gamma and Wu to bf16
// blocks 768..895 : per-(task,r) dots u = Wd·gamma, w = Wd·beta
// blocks 896..1663: per-sample sum/sumsq partials (48 blocks/sample, no atomics)
__global__ __launch_bounds__(256) void prep_stats_kernel(
        const float* __restrict__ Wdn, const float* __restrict__ Wup,
        const float* __restrict__ gamma, const float* __restrict__ beta,
        const float* __restrict__ x,
        float* __restrict__ partials,
        unsigned short* __restrict__ wdg, unsigned short* __restrict__ wu_bf,
        float* __restrict__ u, float* __restrict__ w) {
    int bid = blockIdx.x;
    int tid = threadIdx.x;
    if (bid < 768) {
        int idx = bid * 256 + tid;              // 0..196607 float4 jobs
        const int NF4 = T * R * C / 4;          // 98304
        if (idx < NF4) {
            int c4 = idx % (C / 4);
            float4 v = ((const float4*)Wdn)[idx];
            float4 g = ((const float4*)gamma)[c4];
            ushort4 o;
            o.x = f2bf(v.x * g.x); o.y = f2bf(v.y * g.y);
            o.z = f2bf(v.z * g.z); o.w = f2bf(v.w * g.w);
            *reinterpret_cast<ushort4*>(wdg + idx * 4) = o;
        } else {
            int j = idx - NF4;
            float4 v = ((const float4*)Wup)[j];
            ushort4 o;
            o.x = f2bf(v.x); o.y = f2bf(v.y); o.z = f2bf(v.z); o.w = f2bf(v.w);
            *reinterpret_cast<ushort4*>(wu_bf + j * 4) = o;
        }
    } else if (bid < 896) {
        // 128 blocks x 4 rows: rowid = t*64 + r
        int rowid = (bid - 768) * 4 + (tid >> 6);
        int lane = tid & 63;
        const float* wrow = Wdn + (size_t)rowid * C;
        float su = 0.f, sw = 0.f;
        #pragma unroll
        for (int j = 0; j < 12; j++) {
            int c = lane + j * 64;
            float wv = wrow[c];
            su += wv * gamma[c];
            sw += wv * beta[c];
        }
        for (int off = 32; off > 0; off >>= 1) {
            su += __shfl_down(su, off);
            sw += __shfl_down(sw, off);
        }
        if (lane == 0) { u[rowid] = su; w[rowid] = sw; }
    } else {
        int sblk = bid - 896;
        int b = sblk / NPART, part = sblk % NPART;
        const float4* xp = (const float4*)(x + (size_t)b * NPS);
        float s = 0.f, q = 0.f;
        int base = part * 256 + tid;            // 0..12287
        #pragma unroll 4
        for (int i = 0; i < 64; i++) {
            float4 v = xp[(size_t)i * 12288 + base];
            s += v.x + v.y + v.z + v.w;
            q += v.x*v.x + v.y*v.y + v.z*v.z + v.w*v.w;
        }
        for (int off = 32; off > 0; off >>= 1) {
            s += __shfl_down(s, off);
            q += __shfl_down(q, off);
        }
        __shared__ float ps[4], pq[4];
        int wave = tid >> 6, lane = tid & 63;
        if (lane == 0) { ps[wave] = s; pq[wave] = q; }
        __syncthreads();
        if (tid == 0) {
            float S = 0.f, Q = 0.f;
            #pragma unroll
            for (int wv = 0; wv < 4; wv++) { S += ps[wv]; Q += pq[wv]; }
            partials[(b * NPART + part) * 2]     = S;
            partials[(b * NPART + part) * 2 + 1] = Q;
        }
    }
}

// ---------------- kernel B: fused, async-DMA, 3-buffer prefetch-depth-2 ----------------
// 256 blocks (1/CU), 256 threads = 4 waves. Block = (sample b, chunk of 256 rows),
// 16 tiles of 16 rows. x tile (48KB fp32) staged via global_load_lds, pre-swizzled
// source (XOR (row&7)<<4), 3 buffers / depth-2 prefetch, counted vmcnt.
// GroupNorm folded into weights: h_pre = rstd*(Wdg·x_raw) + (w - rstd*mean*u).
__global__ __launch_bounds__(256, 1) void fused_kernel(
        const float* __restrict__ x, const int* __restrict__ task_ids,
        const float* __restrict__ scales, const float* __restrict__ partials,
        const unsigned short* __restrict__ wdg, const unsigned short* __restrict__ wu_bf,
        const float* __restrict__ u, const float* __restrict__ w,
        float* __restrict__ out) {
    __shared__ char xsb[3 * 49152];            // 144 KiB: 3 x (16 rows x 3072 B)
    __shared__ char hsb[2048];                 // 16 rows x 128 B bf16 h

    int bid = blockIdx.x;
    int b = bid >> 4;
    int chunk = bid & 15;
    int tid = threadIdx.x;
    int wv = tid >> 6, lane = tid & 63;
    int lr = lane & 15, lg = lane >> 4;
    int swz = (lr & 7) << 4;

    int t = task_ids[b];
    float sc = scales[t];

    // reduce this sample's 48 stats partials (every wave, butterfly over 64 lanes)
    float s1 = 0.f, s2 = 0.f;
    if (lane < NPART) {
        float2 v = ((const float2*)(partials + b * 2 * NPART))[lane];
        s1 = v.x; s2 = v.y;
    }
    #pragma unroll
    for (int off = 32; off > 0; off >>= 1) {
        s1 += __shfl_xor(s1, off);
        s2 += __shfl_xor(s2, off);
    }
    float mean = s1 * (1.f / NPS);
    float var  = s2 * (1.f / NPS) - mean * mean;
    float rstd = rsqrtf(var + GN_EPS);

    // persistent A-fragments (weights) in VGPRs
    const unsigned short* wdp = wdg + t * (R * C);
    bf16x8 a1[24];
    #pragma unroll
    for (int k = 0; k < 24; k++)
        a1[k] = *reinterpret_cast<const bf16x8*>(wdp + (wv * 16 + lr) * C + k * 32 + lg * 8);
    const unsigned short* wup = wu_bf + t * (C * R);
    bf16x8 a2[12][2];
    #pragma unroll
    for (int cb = 0; cb < 12; cb++)
        #pragma unroll
        for (int ks = 0; ks < 2; ks++)
            a2[cb][ks] = *reinterpret_cast<const bf16x8*>(
                wup + (wv * 192 + cb * 16 + lr) * R + ks * 32 + lg * 8);

    // gelu bias for this thread's 4 R-channels (r0..r0+3)
    int r0 = wv * 16 + lg * 4;
    float4 u4 = *reinterpret_cast<const float4*>(u + t * 64 + r0);
    float4 w4 = *reinterpret_cast<const float4*>(w + t * 64 + r0);
    float mb = rstd * mean;
    float bias0 = w4.x - mb * u4.x, bias1 = w4.y - mb * u4.y;
    float bias2 = w4.z - mb * u4.z, bias3 = w4.w - mb * u4.w;

    size_t base = (size_t)b * NPS + (size_t)chunk * 256 * C;   // elements
    const char* xbase_c = (const char*)(x + base);
    float* outp = out + base;
    const char* hcb = hsb;

#define STAGE(ldbuf, tileidx) do {                                               \
    const char* _gs = xbase_c + (size_t)(tileidx) * 49152;                       \
    char* _ld = (ldbuf);                                                         \
    _Pragma("unroll")                                                            \
    for (int _jj = 0; _jj < 12; _jj++) {                                         \
        int _j = wv * 12 + _jj;                                                  \
        int _row = _j / 3;                                                       \
        int _sub = _j - _row * 3;                                                \
        int _cb = (_sub * 1024 + lane * 16) ^ ((_row & 7) << 4);                 \
        __builtin_amdgcn_global_load_lds(                                        \
            (const __attribute__((address_space(1))) void*)(_gs + _row * 3072 + _cb), \
            (__attribute__((address_space(3))) void*)(_ld + (size_t)_j * 1024),  \
            16, 0, 0);                                                           \
    }                                                                            \
} while (0)

    char* bufA = xsb;              // tile i (current)
    char* bufB = xsb + 49152;      // tile i+1 (in flight)
    char* bufC = xsb + 98304;      // tile i+2 (stage target)

    STAGE(bufA, 0);
    STAGE(bufB, 1);

    for (int i = 0; i < 16; i++) {
        // drain exactly tile i's 12 loads (issue-order vmcnt arithmetic:
        // steady state leaves next tile's 12 loads + previous iter's 12 stores)
        if (i == 0 || i == 15) asm volatile("s_waitcnt vmcnt(12)" ::: "memory");
        else                   asm volatile("s_waitcnt vmcnt(24)" ::: "memory");
        __builtin_amdgcn_s_barrier();
        if (i + 2 < 16) STAGE(bufC, i + 2);   // fire-and-forget, depth 2

        const char* xb = bufA;

        // ---- GEMM1: G = Wdg · x_raw ; wave wv owns R-rows wv*16..+15 ----
        f32x4 acc1 = {0.f, 0.f, 0.f, 0.f};
        #pragma unroll
        for (int k = 0; k < 24; k++) {
            int cb0 = (k * 128 + lg * 32) ^ swz;
            int cb1 = (k * 128 + lg * 32 + 16) ^ swz;
            f32x4 xv0 = *reinterpret_cast<const f32x4*>(xb + lr * 3072 + cb0);
            f32x4 xv1 = *reinterpret_cast<const f32x4*>(xb + lr * 3072 + cb1);
            bf16x8 bfrag;
            bfrag[0] = (short)f2bf(xv0[0]); bfrag[1] = (short)f2bf(xv0[1]);
            bfrag[2] = (short)f2bf(xv0[2]); bfrag[3] = (short)f2bf(xv0[3]);
            bfrag[4] = (short)f2bf(xv1[0]); bfrag[5] = (short)f2bf(xv1[1]);
            bfrag[6] = (short)f2bf(xv1[2]); bfrag[7] = (short)f2bf(xv1[3]);
            acc1 = __builtin_amdgcn_mfma_f32_16x16x32_bf16(a1[k], bfrag, acc1, 0, 0, 0);
        }

        // ---- gelu(rstd*G + bias) -> hs (bf16, swizzled) ----
        {
            float v0 = rstd * acc1[0] + bias0;
            float v1 = rstd * acc1[1] + bias1;
            float v2 = rstd * acc1[2] + bias2;
            float v3 = rstd * acc1[3] + bias3;
            ushort4 o;
            o.x = f2bf(0.5f * v0 * (1.f + erff(v0 * 0.70710678118f)));
            o.y = f2bf(0.5f * v1 * (1.f + erff(v1 * 0.70710678118f)));
            o.z = f2bf(0.5f * v2 * (1.f + erff(v2 * 0.70710678118f)));
            o.w = f2bf(0.5f * v3 * (1.f + erff(v3 * 0.70710678118f)));
            int byte = lr * 128 + ((wv * 32 + lg * 8) ^ swz);
            *reinterpret_cast<ushort4*>(hsb + byte) = o;
        }
        asm volatile("s_waitcnt lgkmcnt(0)" ::: "memory");
        __builtin_amdgcn_s_barrier();

        // ---- GEMM2: delta = Wu · gelu(h); fused residual from LDS fp32 x ----
        bf16x8 b2[2];
        #pragma unroll
        for (int ks = 0; ks < 2; ks++) {
            int byte = lr * 128 + ((ks * 64 + lg * 16) ^ swz);
            b2[ks] = *reinterpret_cast<const bf16x8*>(hcb + byte);
        }
        size_t ro = (size_t)(i * 16 + lr) * C;
        #pragma unroll
        for (int cb = 0; cb < 12; cb++) {
            f32x4 acc = {0.f, 0.f, 0.f, 0.f};
            acc = __builtin_amdgcn_mfma_f32_16x16x32_bf16(a2[cb][0], b2[0], acc, 0, 0, 0);
            acc = __builtin_amdgcn_mfma_f32_16x16x32_bf16(a2[cb][1], b2[1], acc, 0, 0, 0);
            int c0 = wv * 192 + cb * 16 + lg * 4;
            float4 xr = *reinterpret_cast<const float4*>(xb + lr * 3072 + ((c0 * 4) ^ swz));
            float4 ov;
            ov.x = xr.x + sc * acc[0];
            ov.y = xr.y + sc * acc[1];
            ov.z = xr.z + sc * acc[2];
            ov.w = xr.w + sc * acc[3];
            *reinterpret_cast<float4*>(outp + ro + c0) = ov;
        }

        char* tmp = bufA; bufA = bufB; bufB = bufC; bufC = tmp;
    }
#undef STAGE
}

extern "C" void kernel_launch(void* const* d_in, const int* in_sizes, int n_in,
                              void* d_out, int out_size, void* d_ws, size_t ws_size,
                              hipStream_t stream) {
    const float* x        = (const float*)d_in[0];
    const int*   task_ids = (const int*)d_in[1];
    const float* gamma    = (const float*)d_in[2];
    const float* beta     = (const float*)d_in[3];
    const float* W_down   = (const float*)d_in[4];
    const float* W_up     = (const float*)d_in[5];
    const float* scales   = (const float*)d_in[6];
    float* out = (float*)d_out;

    // workspace: [0,8K) stats partials (768x2 fp32); wdg bf16; wu bf16; u; w
    float* partials = (float*)d_ws;
    unsigned short* wdg   = (unsigned short*)((char*)d_ws + 8192);
    unsigned short* wu_bf = wdg + T * R * C;
    float* u = (float*)((char*)d_ws + 8192 + 2 * T * R * C * sizeof(unsigned short));
    float* w = u + T * R;

    prep_stats_kernel<<<1664, 256, 0, stream>>>(W_down, W_up, gamma, beta, x,
                                                partials, wdg, wu_bf, u, w);
    fused_kernel<<<256, 256, 0, stream>>>(x, task_ids, scales, partials,
                                          wdg, wu_bf, u, w, out);
}

// Round 7
// 116.836 us; speedup vs baseline: 1.8131x; 1.0333x over previous
//
#include <hip/hip_runtime.h>
#include <hip/hip_bf16.h>

#define BATCH 16
#define C 768
#define T 8
#define R 64
#define HW 4096
#define NPS (HW*C)   // 3145728 elements per sample
#define GN_EPS 1e-5f
#define NPART 48     // stats partial blocks per sample

typedef short bf16x8 __attribute__((ext_vector_type(8)));
typedef float f32x4 __attribute__((ext_vector_type(4)));

static __device__ __forceinline__ unsigned short f2bf(float f) {
    __hip_bfloat16 h = __float2bfloat16(f);
    return *reinterpret_cast<unsigned short*>(&h);
}

// ---------------- kernel A: prep (weights) + stats partials, one launch ----------------
__global__ __launch_bounds__(256) void prep_stats_kernel(
        const float* __restrict__ Wdn, const float* __restrict__ Wup,
        const float* __restrict__ gamma, const float* __restrict__ beta,
        const float* __restrict__ x,
        float* __restrict__ partials,
        unsigned short* __restrict__ wdg, unsigned short* __restrict__ wu_bf,
        float* __restrict__ u, float* __restrict__ w) {
    int bid = blockIdx.x;
    int tid = threadIdx.x;
    if (bid < 768) {
        int idx = bid * 256 + tid;              // 0..196607 float4 jobs
        const int NF4 = T * R * C / 4;          // 98304
        if (idx < NF4) {
            int c4 = idx % (C / 4);
            float4 v = ((const float4*)Wdn)[idx];
            float4 g = ((const float4*)gamma)[c4];
            ushort4 o;
            o.x = f2bf(v.x * g.x); o.y = f2bf(v.y * g.y);
            o.z = f2bf(v.z * g.z); o.w = f2bf(v.w * g.w);
            *reinterpret_cast<ushort4*>(wdg + idx * 4) = o;
        } else {
            int j = idx - NF4;
            float4 v = ((const float4*)Wup)[j];
            ushort4 o;
            o.x = f2bf(v.x); o.y = f2bf(v.y); o.z = f2bf(v.z); o.w = f2bf(v.w);
            *reinterpret_cast<ushort4*>(wu_bf + j * 4) = o;
        }
    } else if (bid < 896) {
        int rowid = (bid - 768) * 4 + (tid >> 6);
        int lane = tid & 63;
        const float* wrow = Wdn + (size_t)rowid * C;
        float su = 0.f, sw = 0.f;
        #pragma unroll
        for (int j = 0; j < 12; j++) {
            int c = lane + j * 64;
            float wv = wrow[c];
            su += wv * gamma[c];
            sw += wv * beta[c];
        }
        for (int off = 32; off > 0; off >>= 1) {
            su += __shfl_down(su, off);
            sw += __shfl_down(sw, off);
        }
        if (lane == 0) { u[rowid] = su; w[rowid] = sw; }
    } else {
        int sblk = bid - 896;
        int b = sblk / NPART, part = sblk % NPART;
        const float4* xp = (const float4*)(x + (size_t)b * NPS);
        float s = 0.f, q = 0.f;
        int base = part * 256 + tid;
        #pragma unroll 4
        for (int i = 0; i < 64; i++) {
            float4 v = xp[(size_t)i * 12288 + base];
            s += v.x + v.y + v.z + v.w;
            q += v.x*v.x + v.y*v.y + v.z*v.z + v.w*v.w;
        }
        for (int off = 32; off > 0; off >>= 1) {
            s += __shfl_down(s, off);
            q += __shfl_down(q, off);
        }
        __shared__ float ps[4], pq[4];
        int wave = tid >> 6, lane = tid & 63;
        if (lane == 0) { ps[wave] = s; pq[wave] = q; }
        __syncthreads();
        if (tid == 0) {
            float S = 0.f, Q = 0.f;
            #pragma unroll
            for (int wv = 0; wv < 4; wv++) { S += ps[wv]; Q += pq[wv]; }
            partials[(b * NPART + part) * 2]     = S;
            partials[(b * NPART + part) * 2 + 1] = Q;
        }
    }
}

// ---------------- kernel B: fused, producer-consumer wave specialization ----------------
// 256 blocks (1/CU), 512 threads = 8 waves (2/SIMD).
// Waves 0-3 (producers): async-DMA staging + GEMM1(i) + gelu -> hsb[i&1].
// Waves 4-7 (consumers): GEMM2(i-1) + residual (LDS) + stores, SAME barrier window.
// One s_barrier per iteration; STAGE(i+2) post-barrier keeps the 3-buffer rotation safe.
__global__ __launch_bounds__(512, 1) void fused_kernel(
        const float* __restrict__ x, const int* __restrict__ task_ids,
        const float* __restrict__ scales, const float* __restrict__ partials,
        const unsigned short* __restrict__ wdg, const unsigned short* __restrict__ wu_bf,
        const float* __restrict__ u, const float* __restrict__ w,
        float* __restrict__ out) {
    __shared__ char xsb[3 * 49152];            // 144 KiB: 3 x (16 rows x 3072 B)
    __shared__ char hsb[2][2048];              // double-buffered bf16 h (16 x 64)

    int bid = blockIdx.x;
    int b = bid >> 4;
    int chunk = bid & 15;
    int tid = threadIdx.x;
    int wvid = tid >> 6, lane = tid & 63;
    int lr = lane & 15, lg = lane >> 4;
    int swz = (lr & 7) << 4;

    int t = task_ids[b];
    float sc = scales[t];

    // reduce this sample's 48 stats partials (every wave, butterfly)
    float s1 = 0.f, s2 = 0.f;
    if (lane < NPART) {
        float2 v = ((const float2*)(partials + b * 2 * NPART))[lane];
        s1 = v.x; s2 = v.y;
    }
    #pragma unroll
    for (int off = 32; off > 0; off >>= 1) {
        s1 += __shfl_xor(s1, off);
        s2 += __shfl_xor(s2, off);
    }
    float mean = s1 * (1.f / NPS);
    float var  = s2 * (1.f / NPS) - mean * mean;
    float rstd = rsqrtf(var + GN_EPS);

    size_t base = (size_t)b * NPS + (size_t)chunk * 256 * C;   // elements
    const char* xbase_c = (const char*)(x + base);
    float* outp = out + base;

#define STAGE(ldbuf, tileidx) do {                                               \
    const char* _gs = xbase_c + (size_t)(tileidx) * 49152;                       \
    char* _ld = (ldbuf);                                                         \
    _Pragma("unroll")                                                            \
    for (int _jj = 0; _jj < 12; _jj++) {                                         \
        int _j = pw * 12 + _jj;                                                  \
        int _row = _j / 3;                                                       \
        int _sub = _j - _row * 3;                                                \
        int _cb = (_sub * 1024 + lane * 16) ^ ((_row & 7) << 4);                 \
        __builtin_amdgcn_global_load_lds(                                        \
            (const __attribute__((address_space(1))) void*)(_gs + _row * 3072 + _cb), \
            (__attribute__((address_space(3))) void*)(_ld + (size_t)_j * 1024),  \
            16, 0, 0);                                                           \
    }                                                                            \
} while (0)

    if (wvid < 4) {
        // ======================= PRODUCER =======================
        int pw = wvid;
        const unsigned short* wdp = wdg + t * (R * C);
        bf16x8 a1[24];
        #pragma unroll
        for (int k = 0; k < 24; k++)
            a1[k] = *reinterpret_cast<const bf16x8*>(wdp + (pw * 16 + lr) * C + k * 32 + lg * 8);

        int r0 = pw * 16 + lg * 4;
        float4 u4 = *reinterpret_cast<const float4*>(u + t * 64 + r0);
        float4 w4 = *reinterpret_cast<const float4*>(w + t * 64 + r0);
        float mb = rstd * mean;
        float bias0 = w4.x - mb * u4.x, bias1 = w4.y - mb * u4.y;
        float bias2 = w4.z - mb * u4.z, bias3 = w4.w - mb * u4.w;

        STAGE(xsb, 0);
        STAGE(xsb + 49152, 1);

        for (int i = 0; i < 16; i++) {
            if (i == 15) asm volatile("s_waitcnt vmcnt(0)" ::: "memory");
            else         asm volatile("s_waitcnt vmcnt(12)" ::: "memory");

            const char* xb = xsb + (i % 3) * 49152;
            // GEMM1: two independent accumulator chains
            f32x4 acc1a = {0.f, 0.f, 0.f, 0.f};
            f32x4 acc1b = {0.f, 0.f, 0.f, 0.f};
            #pragma unroll
            for (int k = 0; k < 24; k += 2) {
                #pragma unroll
                for (int kk = 0; kk < 2; kk++) {
                    int kc = k + kk;
                    int cb0 = (kc * 128 + lg * 32) ^ swz;
                    int cb1 = (kc * 128 + lg * 32 + 16) ^ swz;
                    f32x4 xv0 = *reinterpret_cast<const f32x4*>(xb + lr * 3072 + cb0);
                    f32x4 xv1 = *reinterpret_cast<const f32x4*>(xb + lr * 3072 + cb1);
                    bf16x8 bfrag;
                    bfrag[0] = (short)f2bf(xv0[0]); bfrag[1] = (short)f2bf(xv0[1]);
                    bfrag[2] = (short)f2bf(xv0[2]); bfrag[3] = (short)f2bf(xv0[3]);
                    bfrag[4] = (short)f2bf(xv1[0]); bfrag[5] = (short)f2bf(xv1[1]);
                    bfrag[6] = (short)f2bf(xv1[2]); bfrag[7] = (short)f2bf(xv1[3]);
                    if (kk == 0)
                        acc1a = __builtin_amdgcn_mfma_f32_16x16x32_bf16(a1[kc], bfrag, acc1a, 0, 0, 0);
                    else
                        acc1b = __builtin_amdgcn_mfma_f32_16x16x32_bf16(a1[kc], bfrag, acc1b, 0, 0, 0);
                }
            }
            float v0 = rstd * (acc1a[0] + acc1b[0]) + bias0;
            float v1 = rstd * (acc1a[1] + acc1b[1]) + bias1;
            float v2 = rstd * (acc1a[2] + acc1b[2]) + bias2;
            float v3 = rstd * (acc1a[3] + acc1b[3]) + bias3;
            ushort4 o;
            o.x = f2bf(0.5f * v0 * (1.f + erff(v0 * 0.70710678118f)));
            o.y = f2bf(0.5f * v1 * (1.f + erff(v1 * 0.70710678118f)));
            o.z = f2bf(0.5f * v2 * (1.f + erff(v2 * 0.70710678118f)));
            o.w = f2bf(0.5f * v3 * (1.f + erff(v3 * 0.70710678118f)));
            int hbyte = lr * 128 + ((pw * 32 + lg * 8) ^ swz);
            *reinterpret_cast<ushort4*>(hsb[i & 1] + hbyte) = o;

            asm volatile("s_waitcnt lgkmcnt(0)" ::: "memory");
            __builtin_amdgcn_s_barrier();
            if (i + 2 < 16) STAGE(xsb + ((i + 2) % 3) * 49152, i + 2);
        }
    } else {
        // ======================= CONSUMER =======================
        int cw = wvid - 4;
        const unsigned short* wup = wu_bf + t * (C * R);
        bf16x8 a2[12][2];
        #pragma unroll
        for (int cb = 0; cb < 12; cb++)
            #pragma unroll
            for (int ks = 0; ks < 2; ks++)
                a2[cb][ks] = *reinterpret_cast<const bf16x8*>(
                    wup + (cw * 192 + cb * 16 + lr) * R + ks * 32 + lg * 8);

        for (int i = 0; i < 16; i++) {
            if (i > 0) {
                int j = i - 1;
                const char* xb = xsb + (j % 3) * 49152;
                bf16x8 b2[2];
                #pragma unroll
                for (int ks = 0; ks < 2; ks++) {
                    int byte = lr * 128 + ((ks * 64 + lg * 16) ^ swz);
                    b2[ks] = *reinterpret_cast<const bf16x8*>(hsb[j & 1] + byte);
                }
                size_t ro = (size_t)(j * 16 + lr) * C;
                #pragma unroll
                for (int cb = 0; cb < 12; cb++) {
                    f32x4 acc = {0.f, 0.f, 0.f, 0.f};
                    acc = __builtin_amdgcn_mfma_f32_16x16x32_bf16(a2[cb][0], b2[0], acc, 0, 0, 0);
                    acc = __builtin_amdgcn_mfma_f32_16x16x32_bf16(a2[cb][1], b2[1], acc, 0, 0, 0);
                    int c0 = cw * 192 + cb * 16 + lg * 4;
                    float4 xr = *reinterpret_cast<const float4*>(xb + lr * 3072 + ((c0 * 4) ^ swz));
                    float4 ov;
                    ov.x = xr.x + sc * acc[0];
                    ov.y = xr.y + sc * acc[1];
                    ov.z = xr.z + sc * acc[2];
                    ov.w = xr.w + sc * acc[3];
                    *reinterpret_cast<float4*>(outp + ro + c0) = ov;
                }
            }
            __builtin_amdgcn_s_barrier();
        }
        // tail: tile 15 (sealed by the loop's final barrier)
        {
            int j = 15;
            const char* xb = xsb + (j % 3) * 49152;
            bf16x8 b2[2];
            #pragma unroll
            for (int ks = 0; ks < 2; ks++) {
                int byte = lr * 128 + ((ks * 64 + lg * 16) ^ swz);
                b2[ks] = *reinterpret_cast<const bf16x8*>(hsb[j & 1] + byte);
            }
            size_t ro = (size_t)(j * 16 + lr) * C;
            #pragma unroll
            for (int cb = 0; cb < 12; cb++) {
                f32x4 acc = {0.f, 0.f, 0.f, 0.f};
                acc = __builtin_amdgcn_mfma_f32_16x16x32_bf16(a2[cb][0], b2[0], acc, 0, 0, 0);
                acc = __builtin_amdgcn_mfma_f32_16x16x32_bf16(a2[cb][1], b2[1], acc, 0, 0, 0);
                int c0 = cw * 192 + cb * 16 + lg * 4;
                float4 xr = *reinterpret_cast<const float4*>(xb + lr * 3072 + ((c0 * 4) ^ swz));
                float4 ov;
                ov.x = xr.x + sc * acc[0];
                ov.y = xr.y + sc * acc[1];
                ov.z = xr.z + sc * acc[2];
                ov.w = xr.w + sc * acc[3];
                *reinterpret_cast<float4*>(outp + ro + c0) = ov;
            }
        }
    }
#undef STAGE
}

extern "C" void kernel_launch(void* const* d_in, const int* in_sizes, int n_in,
                              void* d_out, int out_size, void* d_ws, size_t ws_size,
                              hipStream_t stream) {
    const float* x        = (const float*)d_in[0];
    const int*   task_ids = (const int*)d_in[1];
    const float* gamma    = (const float*)d_in[2];
    const float* beta     = (const float*)d_in[3];
    const float* W_down   = (const float*)d_in[4];
    const float* W_up     = (const float*)d_in[5];
    const float* scales   = (const float*)d_in[6];
    float* out = (float*)d_out;

    // workspace: [0,8K) stats partials (768x2 fp32); wdg bf16; wu bf16; u; w
    float* partials = (float*)d_ws;
    unsigned short* wdg   = (unsigned short*)((char*)d_ws + 8192);
    unsigned short* wu_bf = wdg + T * R * C;
    float* u = (float*)((char*)d_ws + 8192 + 2 * T * R * C * sizeof(unsigned short));
    float* w = u + T * R;

    prep_stats_kernel<<<1664, 256, 0, stream>>>(W_down, W_up, gamma, beta, x,
                                                partials, wdg, wu_bf, u, w);
    fused_kernel<<<256, 512, 0, stream>>>(x, task_ids, scales, partials,
                                          wdg, wu_bf, u, w, out);
}